// Round 1
// baseline (324.498 us; speedup 1.0000x reference)
//
#include <hip/hip_runtime.h>
#include <math.h>

#define DIMK 2048
#define NSEQ 4096

typedef short bf16x8 __attribute__((ext_vector_type(8)));
typedef float f32x4 __attribute__((ext_vector_type(4)));
typedef unsigned short u16;

__device__ __forceinline__ u16 f32_to_bf16(float f) {
  unsigned u = __float_as_uint(f);
  u += 0x7fffu + ((u >> 16) & 1u);   // round-to-nearest-even
  return (u16)(u >> 16);
}

__device__ __forceinline__ void async16(const u16* g, u16* l) {
  __builtin_amdgcn_global_load_lds(
      (const __attribute__((address_space(1))) unsigned int*)g,
      (__attribute__((address_space(3))) unsigned int*)l,
      16, 0, 0);
}

// -------- fp32 -> bf16 cast, float4 / ushort4 vectorized --------
__global__ __launch_bounds__(256) void cast_f32_bf16(
    const float* __restrict__ in, u16* __restrict__ out, int n4) {
  int i = blockIdx.x * 256 + threadIdx.x;
  if (i >= n4) return;
  float4 v = ((const float4*)in)[i];
  ushort4 o;
  o.x = f32_to_bf16(v.x);
  o.y = f32_to_bf16(v.y);
  o.z = f32_to_bf16(v.z);
  o.w = f32_to_bf16(v.w);
  ((ushort4*)out)[i] = o;
}

// -------- GEMM1: Q = x Wq^T + bq ; K = x Wk^T + bk  (NT, bf16 in, bf16 out)
// 128x128 tile, BK=32, 256 threads (4 waves 2x2), m97 structure.
__global__ __launch_bounds__(256) void gemm_qk(
    const u16* __restrict__ X,
    const u16* __restrict__ Wq, const u16* __restrict__ Wk,
    const float* __restrict__ bq, const float* __restrict__ bk,
    u16* __restrict__ Qo, u16* __restrict__ Ko) {
  const int K = DIMK;
  const u16* Bmat = blockIdx.z ? Wk : Wq;
  const float* bias = blockIdx.z ? bk : bq;
  u16* Out = blockIdx.z ? Ko : Qo;

  __shared__ u16 sA[128 * 32];
  __shared__ u16 sB[128 * 32];

  const int tid = threadIdx.x;
  const int lane = tid & 63;
  const int wid = tid >> 6;
  const int rowBase = blockIdx.y * 128;
  const int colBase = blockIdx.x * 128;

  // staging: chunk c covers row c>>2, k-offset (c&3)*8 (8 bf16 = 16B per lane)
  const u16* gA0 = X + (size_t)(rowBase + (tid >> 2)) * K + (tid & 3) * 8;
  const u16* gB0 = Bmat + (size_t)(colBase + (tid >> 2)) * K + (tid & 3) * 8;
  const u16* gA1 = gA0 + (size_t)64 * K;
  const u16* gB1 = gB0 + (size_t)64 * K;
  u16* lA0 = &sA[tid * 8];
  u16* lA1 = &sA[(tid + 256) * 8];
  u16* lB0 = &sB[tid * 8];
  u16* lB1 = &sB[(tid + 256) * 8];

  const int wm = (wid >> 1) * 64;
  const int wn = (wid & 1) * 64;
  const int fr = lane & 15;
  const int kg = (lane >> 4) * 8;

  f32x4 acc[4][4] = {};

  for (int k0 = 0; k0 < K; k0 += 32) {
    async16(gA0 + k0, lA0);
    async16(gA1 + k0, lA1);
    async16(gB0 + k0, lB0);
    async16(gB1 + k0, lB1);
    __syncthreads();
    bf16x8 af[4], bfv[4];
#pragma unroll
    for (int i = 0; i < 4; ++i) {
      af[i] = *(const bf16x8*)&sA[(wm + i * 16 + fr) * 32 + kg];
      bfv[i] = *(const bf16x8*)&sB[(wn + i * 16 + fr) * 32 + kg];
    }
#pragma unroll
    for (int i = 0; i < 4; ++i)
#pragma unroll
      for (int j = 0; j < 4; ++j)
        acc[i][j] =
            __builtin_amdgcn_mfma_f32_16x16x32_bf16(af[i], bfv[j], acc[i][j], 0, 0, 0);
    __syncthreads();
  }

  // epilogue: C/D layout col=lane&15, row=(lane>>4)*4+reg
  const int rq = (lane >> 4) * 4;
#pragma unroll
  for (int j = 0; j < 4; ++j) {
    const int col = colBase + wn + j * 16 + fr;
    const float bv = bias[col];
#pragma unroll
    for (int i = 0; i < 4; ++i) {
#pragma unroll
      for (int r = 0; r < 4; ++r) {
        const int row = rowBase + wm + i * 16 + rq + r;
        Out[(size_t)row * K + col] = f32_to_bf16(acc[i][j][r] + bv);
      }
    }
  }
}

// -------- GEMM2: scores = scale * Q K^T  (NT, bf16 in, fp32 out) --------
__global__ __launch_bounds__(256) void gemm_scores(
    const u16* __restrict__ Qi, const u16* __restrict__ Ki,
    float* __restrict__ out, float scale) {
  const int K = DIMK;

  __shared__ u16 sA[128 * 32];
  __shared__ u16 sB[128 * 32];

  const int tid = threadIdx.x;
  const int lane = tid & 63;
  const int wid = tid >> 6;
  const int rowBase = blockIdx.y * 128;
  const int colBase = blockIdx.x * 128;

  const u16* gA0 = Qi + (size_t)(rowBase + (tid >> 2)) * K + (tid & 3) * 8;
  const u16* gB0 = Ki + (size_t)(colBase + (tid >> 2)) * K + (tid & 3) * 8;
  const u16* gA1 = gA0 + (size_t)64 * K;
  const u16* gB1 = gB0 + (size_t)64 * K;
  u16* lA0 = &sA[tid * 8];
  u16* lA1 = &sA[(tid + 256) * 8];
  u16* lB0 = &sB[tid * 8];
  u16* lB1 = &sB[(tid + 256) * 8];

  const int wm = (wid >> 1) * 64;
  const int wn = (wid & 1) * 64;
  const int fr = lane & 15;
  const int kg = (lane >> 4) * 8;

  f32x4 acc[4][4] = {};

  for (int k0 = 0; k0 < K; k0 += 32) {
    async16(gA0 + k0, lA0);
    async16(gA1 + k0, lA1);
    async16(gB0 + k0, lB0);
    async16(gB1 + k0, lB1);
    __syncthreads();
    bf16x8 af[4], bfv[4];
#pragma unroll
    for (int i = 0; i < 4; ++i) {
      af[i] = *(const bf16x8*)&sA[(wm + i * 16 + fr) * 32 + kg];
      bfv[i] = *(const bf16x8*)&sB[(wn + i * 16 + fr) * 32 + kg];
    }
#pragma unroll
    for (int i = 0; i < 4; ++i)
#pragma unroll
      for (int j = 0; j < 4; ++j)
        acc[i][j] =
            __builtin_amdgcn_mfma_f32_16x16x32_bf16(af[i], bfv[j], acc[i][j], 0, 0, 0);
    __syncthreads();
  }

  const int rq = (lane >> 4) * 4;
#pragma unroll
  for (int j = 0; j < 4; ++j) {
    const int col = colBase + wn + j * 16 + fr;
#pragma unroll
    for (int i = 0; i < 4; ++i) {
#pragma unroll
      for (int r = 0; r < 4; ++r) {
        const int row = rowBase + wm + i * 16 + rq + r;
        out[(size_t)row * NSEQ + col] = acc[i][j][r] * scale;
      }
    }
  }
}

extern "C" void kernel_launch(void* const* d_in, const int* in_sizes, int n_in,
                              void* d_out, int out_size, void* d_ws, size_t ws_size,
                              hipStream_t stream) {
  const float* x = (const float*)d_in[0];
  const float* Wq = (const float*)d_in[1];
  const float* bq = (const float*)d_in[2];
  const float* Wk = (const float*)d_in[3];
  const float* bk = (const float*)d_in[4];
  // d_in[5], d_in[6] (W_v, b_v) unused — V never reaches the output.
  float* out = (float*)d_out;

  // workspace layout (64 MB total)
  u16* xb = (u16*)d_ws;                       // 4096x2048 bf16 (16 MB)
  u16* wqb = xb + (size_t)NSEQ * DIMK;        // 2048x2048 bf16 (8 MB)
  u16* wkb = wqb + (size_t)DIMK * DIMK;       // 8 MB
  u16* qb = wkb + (size_t)DIMK * DIMK;        // 16 MB
  u16* kb = qb + (size_t)NSEQ * DIMK;         // 16 MB

  cast_f32_bf16<<<(NSEQ * DIMK / 4) / 256, 256, 0, stream>>>(x, xb, NSEQ * DIMK / 4);
  cast_f32_bf16<<<(DIMK * DIMK / 4) / 256, 256, 0, stream>>>(Wq, wqb, DIMK * DIMK / 4);
  cast_f32_bf16<<<(DIMK * DIMK / 4) / 256, 256, 0, stream>>>(Wk, wkb, DIMK * DIMK / 4);

  gemm_qk<<<dim3(DIMK / 128, NSEQ / 128, 2), 256, 0, stream>>>(xb, wqb, wkb, bq, bk,
                                                               qb, kb);

  const float scale = 1.0f / sqrtf((float)DIMK);
  gemm_scores<<<dim3(NSEQ / 128, NSEQ / 128, 1), 256, 0, stream>>>(qb, kb, out, scale);
}

// Round 2
// 288.161 us; speedup vs baseline: 1.1261x; 1.1261x over previous
//
#include <hip/hip_runtime.h>
#include <math.h>

#define DIMK 2048
#define NSEQ 4096

typedef short bf16x8 __attribute__((ext_vector_type(8)));
typedef float f32x4 __attribute__((ext_vector_type(4)));
typedef unsigned short u16;

__device__ __forceinline__ u16 f32_to_bf16(float f) {
  unsigned u = __float_as_uint(f);
  u += 0x7fffu + ((u >> 16) & 1u);   // round-to-nearest-even
  return (u16)(u >> 16);
}

__device__ __forceinline__ void async16(const u16* g, u16* l) {
  __builtin_amdgcn_global_load_lds(
      (const __attribute__((address_space(1))) unsigned int*)g,
      (__attribute__((address_space(3))) unsigned int*)l,
      16, 0, 0);
}

// -------- fused fp32 -> bf16 cast for x, Wq, Wk (one launch) --------
__global__ __launch_bounds__(256) void cast3_f32_bf16(
    const float* __restrict__ x, const float* __restrict__ wq,
    const float* __restrict__ wk, u16* __restrict__ xb,
    u16* __restrict__ wqb, u16* __restrict__ wkb) {
  const int xN4 = NSEQ * DIMK / 4;
  const int wN4 = DIMK * DIMK / 4;
  int i = blockIdx.x * 256 + threadIdx.x;
  const float* src;
  u16* dst;
  int j;
  if (i < xN4) { src = x; dst = xb; j = i; }
  else if (i < xN4 + wN4) { src = wq; dst = wqb; j = i - xN4; }
  else { src = wk; dst = wkb; j = i - xN4 - wN4; }
  float4 v = ((const float4*)src)[j];
  ushort4 o;
  o.x = f32_to_bf16(v.x);
  o.y = f32_to_bf16(v.y);
  o.z = f32_to_bf16(v.z);
  o.w = f32_to_bf16(v.w);
  ((ushort4*)dst)[j] = o;
}

// ---- shared NT bf16 GEMM mainloop: 128x128 tile, BK=64, swizzled LDS ----
// LDS layout: slot s holds (row = s>>3, logical kchunk = (s&7)^(row&7)),
// 8 bf16 per slot. Frag reads thus hit all 32 banks at 2/bank (free).
__device__ __forceinline__ void gemm_mainloop_128(
    const u16* __restrict__ Abase, const u16* __restrict__ Bbase,
    u16* sA, u16* sB, f32x4 acc[4][4], int tid, int wm, int wn, int fr,
    int kq /* lane>>4 */) {
  const int K = DIMK;
  // staging addresses: 4 calls per tile, call c covers slots c*256+tid
  int rowS[4], glOff[4];
#pragma unroll
  for (int c = 0; c < 4; ++c) {
    int s = c * 256 + tid;
    int row = s >> 3;
    int l = (s & 7) ^ (row & 7);     // logical kchunk fetched into this slot
    rowS[c] = s;                      // LDS slot
    glOff[c] = row * K + l * 8;       // global element offset (+k0 later)
  }
  // frag-read column offsets (elements) for k-step 0/1: phys = l ^ (fr&7)
  const int f7 = fr & 7;
  int cA0 = ((0 * 4 + kq) ^ f7) * 8;
  int cA1 = ((1 * 4 + kq) ^ f7) * 8;

  for (int k0 = 0; k0 < K; k0 += 64) {
#pragma unroll
    for (int c = 0; c < 4; ++c) {
      async16(Abase + glOff[c] + k0, sA + rowS[c] * 8);
      async16(Bbase + glOff[c] + k0, sB + rowS[c] * 8);
    }
    __syncthreads();
#pragma unroll
    for (int ks = 0; ks < 2; ++ks) {
      const int cc = ks ? cA1 : cA0;
      bf16x8 af[4], bfv[4];
#pragma unroll
      for (int i = 0; i < 4; ++i) {
        af[i] = *(const bf16x8*)&sA[(wm + i * 16 + fr) * 64 + cc];
        bfv[i] = *(const bf16x8*)&sB[(wn + i * 16 + fr) * 64 + cc];
      }
#pragma unroll
      for (int i = 0; i < 4; ++i)
#pragma unroll
        for (int j = 0; j < 4; ++j)
          acc[i][j] = __builtin_amdgcn_mfma_f32_16x16x32_bf16(af[i], bfv[j],
                                                              acc[i][j], 0, 0, 0);
    }
    __syncthreads();
  }
}

// -------- GEMM1: Q = x Wq^T + bq ; K = x Wk^T + bk  (z selects) --------
__global__ __launch_bounds__(256) void gemm_qk(
    const u16* __restrict__ X,
    const u16* __restrict__ Wq, const u16* __restrict__ Wk,
    const float* __restrict__ bq, const float* __restrict__ bk,
    u16* __restrict__ Qo, u16* __restrict__ Ko) {
  const u16* Bmat = blockIdx.z ? Wk : Wq;
  const float* bias = blockIdx.z ? bk : bq;
  u16* Out = blockIdx.z ? Ko : Qo;

  __shared__ u16 sA[128 * 64];
  __shared__ u16 sB[128 * 64];

  const int tid = threadIdx.x;
  const int lane = tid & 63;
  const int wid = tid >> 6;
  const int rowBase = blockIdx.y * 128;
  const int colBase = blockIdx.x * 128;
  const int wm = (wid >> 1) * 64;
  const int wn = (wid & 1) * 64;
  const int fr = lane & 15;
  const int kq = lane >> 4;

  f32x4 acc[4][4] = {};
  gemm_mainloop_128(X + (size_t)rowBase * DIMK, Bmat + (size_t)colBase * DIMK,
                    sA, sB, acc, tid, wm, wn, fr, kq);

  const int rq = kq * 4;
#pragma unroll
  for (int j = 0; j < 4; ++j) {
    const int col = colBase + wn + j * 16 + fr;
    const float bv = bias[col];
#pragma unroll
    for (int i = 0; i < 4; ++i) {
#pragma unroll
      for (int r = 0; r < 4; ++r) {
        const int row = rowBase + wm + i * 16 + rq + r;
        Out[(size_t)row * DIMK + col] = f32_to_bf16(acc[i][j][r] + bv);
      }
    }
  }
}

// -------- GEMM2: scores = scale * Q K^T  (bf16 in, fp32 out) --------
__global__ __launch_bounds__(256) void gemm_scores(
    const u16* __restrict__ Qi, const u16* __restrict__ Ki,
    float* __restrict__ out, float scale) {
  __shared__ u16 sA[128 * 64];
  __shared__ u16 sB[128 * 64];

  const int tid = threadIdx.x;
  const int lane = tid & 63;
  const int wid = tid >> 6;
  const int rowBase = blockIdx.y * 128;
  const int colBase = blockIdx.x * 128;
  const int wm = (wid >> 1) * 64;
  const int wn = (wid & 1) * 64;
  const int fr = lane & 15;
  const int kq = lane >> 4;

  f32x4 acc[4][4] = {};
  gemm_mainloop_128(Qi + (size_t)rowBase * DIMK, Ki + (size_t)colBase * DIMK,
                    sA, sB, acc, tid, wm, wn, fr, kq);

  const int rq = kq * 4;
#pragma unroll
  for (int j = 0; j < 4; ++j) {
    const int col = colBase + wn + j * 16 + fr;
#pragma unroll
    for (int i = 0; i < 4; ++i) {
#pragma unroll
      for (int r = 0; r < 4; ++r) {
        const int row = rowBase + wm + i * 16 + rq + r;
        out[(size_t)row * NSEQ + col] = acc[i][j][r] * scale;
      }
    }
  }
}

extern "C" void kernel_launch(void* const* d_in, const int* in_sizes, int n_in,
                              void* d_out, int out_size, void* d_ws, size_t ws_size,
                              hipStream_t stream) {
  const float* x = (const float*)d_in[0];
  const float* Wq = (const float*)d_in[1];
  const float* bq = (const float*)d_in[2];
  const float* Wk = (const float*)d_in[3];
  const float* bk = (const float*)d_in[4];
  // d_in[5], d_in[6] (W_v, b_v) unused — V never reaches the output.
  float* out = (float*)d_out;

  // workspace layout (64 MB total)
  u16* xb = (u16*)d_ws;                       // 4096x2048 bf16 (16 MB)
  u16* wqb = xb + (size_t)NSEQ * DIMK;        // 2048x2048 bf16 (8 MB)
  u16* wkb = wqb + (size_t)DIMK * DIMK;       // 8 MB
  u16* qb = wkb + (size_t)DIMK * DIMK;        // 16 MB
  u16* kb = qb + (size_t)NSEQ * DIMK;         // 16 MB

  const int totalN4 = (NSEQ * DIMK + 2 * DIMK * DIMK) / 4;
  cast3_f32_bf16<<<totalN4 / 256, 256, 0, stream>>>(x, Wq, Wk, xb, wqb, wkb);

  gemm_qk<<<dim3(DIMK / 128, NSEQ / 128, 2), 256, 0, stream>>>(xb, wqb, wkb, bq, bk,
                                                               qb, kb);

  const float scale = 1.0f / sqrtf((float)DIMK);
  gemm_scores<<<dim3(NSEQ / 128, NSEQ / 128, 1), 256, 0, stream>>>(qb, kb, out, scale);
}